// Round 5
// baseline (588.514 us; speedup 1.0000x reference)
//
#include <hip/hip_runtime.h>
#include <hip/hip_bf16.h>
#include <stdint.h>
#include <stddef.h>

#define B_ 8
#define T_ 4096
#define D_ 1024
#define H_ 1024
#define M_ (B_*T_)      // 32768
#define K_ 1024
#define CHUNK 32
#define NCHUNK 128
#define NWGF ((M_/128)*(H_/128))   // 2048

typedef __attribute__((ext_vector_type(8))) __bf16 bf16v8;
typedef __attribute__((ext_vector_type(4))) float f32x4;
typedef __attribute__((ext_vector_type(8))) unsigned short u16x8;

// LDS (bytes): slot s at s*65536; regions per slot: A=0, Bf=16K, Bi=32K, Bh=48K.
// Each region: [row(128)][64 bf16] with st-16x32 XOR swizzle (byte ^= (row&7)<<4).
#define QA  0
#define QBF 16384
#define QBI 32768
#define QBH 49152
#define SLOT 65536
#define LDS_BYTES 131072

#define FENCE() asm volatile("" ::: "memory")
#define SBAR()  __builtin_amdgcn_s_barrier()
#define STG(p, d) __builtin_amdgcn_global_load_lds(                        \
    (const __attribute__((address_space(1))) void*)(p),                    \
    (__attribute__((address_space(3))) void*)(d), 16, 0, 0)

__device__ __forceinline__ unsigned short f2bf(float f) {
  union { float f; unsigned u; } x; x.f = f;
  return (unsigned short)((x.u + 0x7fffu + ((x.u >> 16) & 1u)) >> 16);
}

// ---------------- converts ----------------
__global__ __launch_bounds__(256) void cvt_x(const float* __restrict__ src,
                                             unsigned short* __restrict__ dst) {
  int i = blockIdx.x * 256 + threadIdx.x;      // 8 elems each
  const float4* s = (const float4*)src;
  float4 a = s[i*2], b = s[i*2+1];
  u16x8 o;
  o[0]=f2bf(a.x); o[1]=f2bf(a.y); o[2]=f2bf(a.z); o[3]=f2bf(a.w);
  o[4]=f2bf(b.x); o[5]=f2bf(b.y); o[6]=f2bf(b.z); o[7]=f2bf(b.w);
  *(u16x8*)(dst + (size_t)i*8) = o;
}

__global__ __launch_bounds__(256) void cvt_w(const float* __restrict__ w0,
                                             const float* __restrict__ w1,
                                             const float* __restrict__ w2,
                                             unsigned short* __restrict__ dst) {
  int i = blockIdx.x * 256 + threadIdx.x;
  int seg = i >> 17;
  int off = i & 131071;
  const float* src = (seg == 0) ? w0 : (seg == 1) ? w1 : w2;
  const float4* s = (const float4*)src;
  float4 a = s[off*2], b = s[off*2+1];
  u16x8 o;
  o[0]=f2bf(a.x); o[1]=f2bf(a.y); o[2]=f2bf(a.z); o[3]=f2bf(a.w);
  o[4]=f2bf(b.x); o[5]=f2bf(b.y); o[6]=f2bf(b.z); o[7]=f2bf(b.w);
  *(u16x8*)(dst + (size_t)i*8) = o;
}

// ---------------- fused GEMM+gates helpers ----------------
__device__ __forceinline__ void rdA8(const char* rbase, int wm, int lr, int cbL,
                                     bf16v8 af[4][2]) {
  #pragma unroll
  for (int i = 0; i < 4; ++i)
    #pragma unroll
    for (int kk = 0; kk < 2; ++kk) {
      int rr = wm*64 + i*16 + lr;
      int cb = kk*64 + cbL;
      af[i][kk] = *(const bf16v8*)(rbase + rr*128 + (cb ^ ((rr & 7) << 4)));
    }
}

__device__ __forceinline__ void rdB4(const char* rbase, int wn, int lr, int cbL,
                                     bf16v8 b[2][2]) {
  #pragma unroll
  for (int j = 0; j < 2; ++j)
    #pragma unroll
    for (int kk = 0; kk < 2; ++kk) {
      int rr = wn*32 + j*16 + lr;
      int cb = kk*64 + cbL;
      b[j][kk] = *(const bf16v8*)(rbase + rr*128 + (cb ^ ((rr & 7) << 4)));
    }
}

__device__ __forceinline__ void mm16(f32x4 acc[4][2], bf16v8 af[4][2],
                                     bf16v8 b[2][2]) {
  __builtin_amdgcn_s_setprio(1);
  #pragma unroll
  for (int i = 0; i < 4; ++i)
    #pragma unroll
    for (int j = 0; j < 2; ++j)
      #pragma unroll
      for (int kk = 0; kk < 2; ++kk)
        acc[i][j] = __builtin_amdgcn_mfma_f32_16x16x32_bf16(af[i][kk], b[j][kk], acc[i][j], 0, 0, 0);
  __builtin_amdgcn_s_setprio(0);
}

__device__ __forceinline__ void gate_eval(float vzf, float vzi, float vzh,
                                          float& f, float& v) {
  float spf = fmaxf(-vzf, 0.f) + __logf(1.f + __expf(-fabsf(vzf)));
  float spi = fmaxf(-vzi, 0.f) + __logf(1.f + __expf(-fabsf(vzi)));
  float d   = spf - spi;
  float l1  = __logf(1.f + __expf(-fabsf(d)));
  f = __expf(-(fmaxf(d, 0.f) + l1));
  float iv = __expf(-(fmaxf(-d, 0.f) + l1));
  float gv = (vzh >= 0.f) ? (vzh + 0.5f) : 1.f/(1.f + __expf(-vzh));
  v = iv * gv;
}

// Full K-step: read slot RD, stage next tile into WR slot (dest offset SOFF),
// KB = byte offset added to the staging pointers (0 for even step, 128 odd).
// vmcnt ledger (instr counts): start={BI,BH}cur(4); P0 +{A,BF}next(4)=8, wait 6
// -> BIcur landed; P1 +BInext=8, wait 6 -> BHcur landed; P2 +BHnext=8, wait 4
// -> {A,BF}next landed; invariant restored.
#define STEP_FULL(RD, SOFF, KB)                                              \
  {                                                                          \
    const char* rd = smem + (RD)*SLOT;                                       \
    rdA8(rd + QA,  wm, lr, cbL, af);                                         \
    rdB4(rd + QBF, wn, lr, cbL, bF);                                         \
    STG(pA0 + (KB), dA0 + (SOFF)); STG(pA1 + (KB), dA1 + (SOFF));            \
    STG(pF0 + (KB), dF0 + (SOFF)); STG(pF1 + (KB), dF1 + (SOFF));            \
    FENCE();                                                                 \
    mm16(accF, af, bF);                                                      \
    asm volatile("s_waitcnt vmcnt(6)" ::: "memory"); SBAR(); FENCE();        \
    rdB4(rd + QBI, wn, lr, cbL, bI);                                         \
    STG(pI0 + (KB), dI0 + (SOFF)); STG(pI1 + (KB), dI1 + (SOFF));            \
    FENCE();                                                                 \
    mm16(accI, af, bI);                                                      \
    asm volatile("s_waitcnt vmcnt(6)" ::: "memory"); SBAR(); FENCE();        \
    rdB4(rd + QBH, wn, lr, cbL, bH);                                         \
    STG(pH0 + (KB), dH0 + (SOFF)); STG(pH1 + (KB), dH1 + (SOFF));            \
    FENCE();                                                                 \
    mm16(accH, af, bH);                                                      \
    asm volatile("s_waitcnt vmcnt(4)" ::: "memory"); SBAR(); FENCE();        \
  }

__global__ __launch_bounds__(512, 2) void gemm_fused(
    const unsigned short* __restrict__ Abf,   // [M][K] bf16
    const unsigned short* __restrict__ Wc,    // [3][H][K] bf16
    const float* __restrict__ bf_, const float* __restrict__ bi_,
    const float* __restrict__ bh_,
    uint32_t* __restrict__ fv)                // [M][H] packed {f:lo16, v:hi16}
{
  extern __shared__ char smem[];
  int tid = threadIdx.x;
  int bid = blockIdx.x;
  int swz = (bid & 7) * (NWGF/8) + (bid >> 3);  // bijective: NWGF%8==0
  int tn = swz & 7, tm = swz >> 3;
  int m0 = tm*128, n0 = tn*128;
  int lane = tid & 63, wid = tid >> 6;
  int wm = wid >> 2, wn = wid & 3;             // 2 x 4 waves
  int lr = lane & 15, lhi = lane >> 4;
  int cbL = lhi * 16;

  const unsigned short* Ag  = Abf + (size_t)m0 * K_;
  const unsigned short* BFg = Wc + (size_t)n0 * K_;
  const unsigned short* BIg = Wc + (size_t)(H_ + n0) * K_;
  const unsigned short* BHg = Wc + (size_t)(2*H_ + n0) * K_;

  // hoisted per-lane staging addresses (computed ONCE)
  int o0 = tid*16, o1 = o0 + 8192;
  int r0 = o0 >> 7, c0 = o0 & 127;
  int r1 = o1 >> 7, c1 = o1 & 127;
  size_t lo0 = (size_t)r0*K_ + (size_t)((c0 ^ ((r0 & 7) << 4)) >> 1);
  size_t lo1 = (size_t)r1*K_ + (size_t)((c1 ^ ((r1 & 7) << 4)) >> 1);
  const char* pA0 = (const char*)(Ag  + lo0);
  const char* pA1 = (const char*)(Ag  + lo1);
  const char* pF0 = (const char*)(BFg + lo0);
  const char* pF1 = (const char*)(BFg + lo1);
  const char* pI0 = (const char*)(BIg + lo0);
  const char* pI1 = (const char*)(BIg + lo1);
  const char* pH0 = (const char*)(BHg + lo0);
  const char* pH1 = (const char*)(BHg + lo1);
  char* dA0 = smem + QA  + o0;  char* dA1 = smem + QA  + o1;   // slot0 dests
  char* dF0 = smem + QBF + o0;  char* dF1 = smem + QBF + o1;
  char* dI0 = smem + QBI + o0;  char* dI1 = smem + QBI + o1;
  char* dH0 = smem + QBH + o0;  char* dH1 = smem + QBH + o1;

  f32x4 accF[4][2] = {}, accI[4][2] = {}, accH[4][2] = {};
  bf16v8 af[4][2], bF[2][2], bI[2][2], bH[2][2];

  // prologue: stage tile 0 into slot 0
  STG(pA0, dA0); STG(pA1, dA1);
  STG(pF0, dF0); STG(pF1, dF1);
  STG(pI0, dI0); STG(pI1, dI1);
  STG(pH0, dH0); STG(pH1, dH1);
  pA0 += 128; pA1 += 128; pF0 += 128; pF1 += 128;   // -> tile 1
  pI0 += 128; pI1 += 128; pH0 += 128; pH1 += 128;
  asm volatile("s_waitcnt vmcnt(4)" ::: "memory");
  SBAR(); FENCE();

  // steps t=0..13 (7 double-steps); stage tiles 1..14
  for (int tt = 0; tt < 7; ++tt) {
    STEP_FULL(0, SLOT, 0)      // even step: read slot0, stage into slot1
    STEP_FULL(1, 0, 128)       // odd step: read slot1, stage into slot0
    pA0 += 256; pA1 += 256; pF0 += 256; pF1 += 256;
    pI0 += 256; pI1 += 256; pH0 += 256; pH1 += 256;
  }
  // step 14: read slot0, stage tile 15 into slot1
  STEP_FULL(0, SLOT, 0)
  // step 15 (tail): read slot1, no staging; waits 2 / 0
  {
    const char* rd = smem + SLOT;
    rdA8(rd + QA,  wm, lr, cbL, af);
    rdB4(rd + QBF, wn, lr, cbL, bF);
    FENCE();
    mm16(accF, af, bF);
    asm volatile("s_waitcnt vmcnt(2)" ::: "memory"); SBAR(); FENCE();
    rdB4(rd + QBI, wn, lr, cbL, bI);
    FENCE();
    mm16(accI, af, bI);
    asm volatile("s_waitcnt vmcnt(0)" ::: "memory"); SBAR(); FENCE();
    rdB4(rd + QBH, wn, lr, cbL, bH);
    FENCE();
    mm16(accH, af, bH);
  }

  // epilogue: gate math in-register, write packed bf16x2 {f, v}
  float bfv[2], biv[2], bhv[2];
  #pragma unroll
  for (int j = 0; j < 2; ++j) {
    int col = n0 + wn*32 + j*16 + lr;
    bfv[j] = bf_[col]; biv[j] = bi_[col]; bhv[j] = bh_[col];
  }
  #pragma unroll
  for (int i = 0; i < 4; ++i)
    #pragma unroll
    for (int j = 0; j < 2; ++j) {
      int col = n0 + wn*32 + j*16 + lr;
      int row0 = m0 + wm*64 + i*16 + lhi*4;
      #pragma unroll
      for (int r = 0; r < 4; ++r) {
        float f, v;
        gate_eval(accF[i][j][r] + bfv[j], accI[i][j][r] + biv[j],
                  accH[i][j][r] + bhv[j], f, v);
        fv[(size_t)(row0 + r)*H_ + col] =
            (uint32_t)f2bf(f) | ((uint32_t)f2bf(v) << 16);
      }
    }
}

// ---------------- phase A: per-chunk (A,S) partials from packed fv ----------
__global__ __launch_bounds__(256) void scan_phaseA(
    const uint32_t* __restrict__ fv,
    float* __restrict__ Aw, float* __restrict__ Sw)
{
  int blk = blockIdx.x;                 // 1024 = b*128 + c
  int c = blk & 127, b = blk >> 7;
  int h4 = threadIdx.x * 4;
  size_t base = ((size_t)b*T_ + (size_t)c*CHUNK)*H_ + h4;
  float Ap[4] = {1.f,1.f,1.f,1.f}, S[4] = {0.f,0.f,0.f,0.f};
  uint4 pk = *(const uint4*)(fv + base);
  for (int t = 0; t < CHUNK; ++t) {
    uint4 nx = pk;
    if (t + 1 < CHUNK) nx = *(const uint4*)(fv + base + (size_t)(t+1)*H_);
    uint32_t w[4] = {pk.x, pk.y, pk.z, pk.w};
    #pragma unroll
    for (int u = 0; u < 4; ++u) {
      union { uint32_t u; float f; } cf, cv;
      cf.u = (w[u] & 0xffffu) << 16;
      cv.u = w[u] & 0xffff0000u;
      S[u] = fmaf(cf.f, S[u], cv.f);
      Ap[u] *= cf.f;
    }
    pk = nx;
  }
  size_t widx = ((size_t)b*NCHUNK + c)*H_ + h4;
  *(float4*)(Aw + widx) = make_float4(Ap[0], Ap[1], Ap[2], Ap[3]);
  *(float4*)(Sw + widx) = make_float4(S[0], S[1], S[2], S[3]);
}

// ---------------- phase B: cross-chunk prefix (tiny) ------------------------
__global__ __launch_bounds__(256) void scan_phaseB(
    const float* __restrict__ Aw, const float* __restrict__ Sw,
    const float* __restrict__ h0, float* __restrict__ Cw)
{
  int i = blockIdx.x*256 + threadIdx.x;    // 0..2047
  int b = i >> 8;
  int h4 = (i & 255) * 4;
  float4 x0 = *(const float4*)(h0 + (size_t)b*H_ + h4);
  float run[4];
  const float* px = (const float*)&x0;
  #pragma unroll
  for (int u = 0; u < 4; ++u)
    run[u] = (px[u] >= 0.f) ? (px[u] + 0.5f) : 1.f/(1.f + __expf(-px[u]));
  for (int c = 0; c < NCHUNK; ++c) {
    size_t idx = ((size_t)b*NCHUNK + c)*H_ + h4;
    *(float4*)(Cw + idx) = make_float4(run[0], run[1], run[2], run[3]);
    float4 av = *(const float4*)(Aw + idx);
    float4 sv = *(const float4*)(Sw + idx);
    const float* pa = (const float*)&av;
    const float* ps = (const float*)&sv;
    #pragma unroll
    for (int u = 0; u < 4; ++u) run[u] = fmaf(pa[u], run[u], ps[u]);
  }
}

// ---------------- phase C: replay with carry, write h -----------------------
__global__ __launch_bounds__(256) void scan_phaseC(
    const uint32_t* __restrict__ fv, const float* __restrict__ Cw,
    float* __restrict__ out)
{
  int blk = blockIdx.x;
  int c = blk & 127, b = blk >> 7;
  int h4 = threadIdx.x * 4;
  float4 cw = *(const float4*)(Cw + ((size_t)b*NCHUNK + c)*H_ + h4);
  float hh[4];
  const float* pc = (const float*)&cw;
  #pragma unroll
  for (int u = 0; u < 4; ++u) hh[u] = pc[u];
  size_t base = ((size_t)b*T_ + (size_t)c*CHUNK)*H_ + h4;
  uint4 pk = *(const uint4*)(fv + base);
  for (int t = 0; t < CHUNK; ++t) {
    uint4 nx = pk;
    if (t + 1 < CHUNK) nx = *(const uint4*)(fv + base + (size_t)(t+1)*H_);
    uint32_t w[4] = {pk.x, pk.y, pk.z, pk.w};
    #pragma unroll
    for (int u = 0; u < 4; ++u) {
      union { uint32_t u; float f; } cf, cv;
      cf.u = (w[u] & 0xffffu) << 16;
      cv.u = w[u] & 0xffff0000u;
      hh[u] = fmaf(cf.f, hh[u], cv.f);
    }
    *(float4*)(out + base + (size_t)t*H_) = make_float4(hh[0], hh[1], hh[2], hh[3]);
    pk = nx;
  }
}

extern "C" void kernel_launch(void* const* d_in, const int* in_sizes, int n_in,
                              void* d_out, int out_size, void* d_ws, size_t ws_size,
                              hipStream_t stream) {
  const float* x   = (const float*)d_in[0];
  const float* h0  = (const float*)d_in[1];
  const float* W_f = (const float*)d_in[2];
  const float* b_f = (const float*)d_in[3];
  const float* W_i = (const float*)d_in[4];
  const float* b_i = (const float*)d_in[5];
  const float* W_h = (const float*)d_in[6];
  const float* b_h = (const float*)d_in[7];
  float* out = (float*)d_out;

  char* ws = (char*)d_ws;
  unsigned short* xb = (unsigned short*)ws;                         // 67.1 MB
  unsigned short* Wc = (unsigned short*)(ws + (size_t)M_*K_*2);     // 6.3 MB
  uint32_t* fv = (uint32_t*)(ws + (size_t)M_*K_*2 + (size_t)3*H_*K_*2); // 134.2 MB
  float* Aw = (float*)(fv + (size_t)M_*H_);                         // 4 MB
  float* Sw = Aw + (size_t)B_*NCHUNK*H_;                            // 4 MB
  float* Cw = Sw + (size_t)B_*NCHUNK*H_;                            // 4 MB

  (void)hipFuncSetAttribute((const void*)gemm_fused,
      hipFuncAttributeMaxDynamicSharedMemorySize, LDS_BYTES);

  cvt_x<<<M_*K_/8/256, 256, 0, stream>>>(x, xb);
  cvt_w<<<3*H_*K_/8/256, 256, 0, stream>>>(W_f, W_i, W_h, Wc);

  gemm_fused<<<NWGF, 512, LDS_BYTES, stream>>>(xb, Wc, b_f, b_i, b_h, fv);

  scan_phaseA<<<B_*NCHUNK, 256, 0, stream>>>(fv, Aw, Sw);
  scan_phaseB<<<B_*H_/4/256, 256, 0, stream>>>(Aw, Sw, h0, Cw);
  scan_phaseC<<<B_*NCHUNK, 256, 0, stream>>>(fv, Cw, out);
}

// Round 8
// 582.640 us; speedup vs baseline: 1.0101x; 1.0101x over previous
//
#include <hip/hip_runtime.h>
#include <hip/hip_bf16.h>
#include <stdint.h>
#include <stddef.h>

#define B_ 8
#define T_ 4096
#define D_ 1024
#define H_ 1024
#define M_ (B_*T_)      // 32768
#define K_ 1024
#define CHUNK 64
#define NCHUNK 64
#define NWGF ((M_/128)*(H_/128))   // 2048

typedef __attribute__((ext_vector_type(8))) __bf16 bf16v8;
typedef __attribute__((ext_vector_type(4))) float f32x4;
typedef __attribute__((ext_vector_type(8))) unsigned short u16x8;

// LDS (bytes): slot s at s*65536; regions per slot: A=0(16K), Bf=16K, Bi=32K, Bh=48K.
// Each region: [row(128)][64 bf16 = 128B] with XOR swizzle (byte ^= (row&7)<<4).
#define QA  0
#define QBF 16384
#define QBI 32768
#define QBH 49152
#define SLOT 65536
#define LDS_BYTES 131072

#define FENCE() asm volatile("" ::: "memory")
#define SBAR()  __builtin_amdgcn_s_barrier()
#define STG(p, d) __builtin_amdgcn_global_load_lds(                        \
    (const __attribute__((address_space(1))) void*)(p),                    \
    (__attribute__((address_space(3))) void*)(d), 16, 0, 0)

__device__ __forceinline__ unsigned short f2bf(float f) {
  union { float f; unsigned u; } x; x.f = f;
  return (unsigned short)((x.u + 0x7fffu + ((x.u >> 16) & 1u)) >> 16);
}

// ---------------- combined f32->bf16 convert (x and 3 weight mats) ----------
__global__ __launch_bounds__(256) void cvt_all(
    const float* __restrict__ x,
    const float* __restrict__ w0, const float* __restrict__ w1,
    const float* __restrict__ w2,
    unsigned short* __restrict__ xb, unsigned short* __restrict__ wb) {
  int i = blockIdx.x * 256 + threadIdx.x;      // 8 elems each
  const int NX = M_*K_/8;
  const float* src; unsigned short* dst; int off;
  if (i < NX) { src = x; dst = xb; off = i; }
  else {
    int j = i - NX; int seg = j >> 17; off = j & 131071;
    src = (seg == 0) ? w0 : (seg == 1) ? w1 : w2;
    dst = wb + (size_t)seg * H_ * K_;
  }
  const float4* s = (const float4*)src;
  float4 a = s[off*2], b = s[off*2+1];
  u16x8 o;
  o[0]=f2bf(a.x); o[1]=f2bf(a.y); o[2]=f2bf(a.z); o[3]=f2bf(a.w);
  o[4]=f2bf(b.x); o[5]=f2bf(b.y); o[6]=f2bf(b.z); o[7]=f2bf(b.w);
  *(u16x8*)(dst + (size_t)off*8) = o;
}

// ---------------- fused GEMM+gates helpers ----------------
__device__ __forceinline__ void rdA8(const char* rbase, int wm, int lr, int cbL,
                                     bf16v8 af[4][2]) {
  #pragma unroll
  for (int i = 0; i < 4; ++i)
    #pragma unroll
    for (int kk = 0; kk < 2; ++kk) {
      int rr = wm*64 + i*16 + lr;
      int cb = kk*64 + cbL;
      af[i][kk] = *(const bf16v8*)(rbase + rr*128 + (cb ^ ((rr & 7) << 4)));
    }
}

__device__ __forceinline__ void rdB4(const char* rbase, int wn, int lr, int cbL,
                                     bf16v8 b[2][2]) {
  #pragma unroll
  for (int j = 0; j < 2; ++j)
    #pragma unroll
    for (int kk = 0; kk < 2; ++kk) {
      int rr = wn*32 + j*16 + lr;
      int cb = kk*64 + cbL;
      b[j][kk] = *(const bf16v8*)(rbase + rr*128 + (cb ^ ((rr & 7) << 4)));
    }
}

__device__ __forceinline__ void mm16(f32x4 acc[4][2], bf16v8 af[4][2],
                                     bf16v8 b[2][2]) {
  #pragma unroll
  for (int i = 0; i < 4; ++i)
    #pragma unroll
    for (int j = 0; j < 2; ++j)
      #pragma unroll
      for (int kk = 0; kk < 2; ++kk)
        acc[i][j] = __builtin_amdgcn_mfma_f32_16x16x32_bf16(af[i][kk], b[j][kk], acc[i][j], 0, 0, 0);
}

__device__ __forceinline__ void gate_eval(float vzf, float vzi, float vzh,
                                          float& f, float& v) {
  float spf = fmaxf(-vzf, 0.f) + __logf(1.f + __expf(-fabsf(vzf)));
  float spi = fmaxf(-vzi, 0.f) + __logf(1.f + __expf(-fabsf(vzi)));
  float d   = spf - spi;
  float l1  = __logf(1.f + __expf(-fabsf(d)));
  f = __expf(-(fmaxf(d, 0.f) + l1));
  float iv = __expf(-(fmaxf(-d, 0.f) + l1));
  float gv = (vzh >= 0.f) ? (vzh + 0.5f) : 1.f/(1.f + __expf(-vzh));
  v = iv * gv;
}

// One K-step, single barrier: [wait vmcnt(0) (stages are a full step old);
// barrier; stage tile t+1 (8 STG); read 20 frags of tile t; 48 MFMA].
// WAR-safe: stage targets slot s^1; every wave's slot-s^1 reads (step t-1)
// data-completed before it reached this barrier (lgkm before MFMA issue).
#define KSTEP(RD, SOFF, KB, ST)                                              \
  {                                                                          \
    asm volatile("s_waitcnt vmcnt(0)" ::: "memory");                         \
    SBAR(); FENCE();                                                         \
    if (ST) {                                                                \
      STG(pA0 + (KB), dA0 + (SOFF)); STG(pA1 + (KB), dA1 + (SOFF));          \
      STG(pF0 + (KB), dF0 + (SOFF)); STG(pF1 + (KB), dF1 + (SOFF));          \
      STG(pI0 + (KB), dI0 + (SOFF)); STG(pI1 + (KB), dI1 + (SOFF));          \
      STG(pH0 + (KB), dH0 + (SOFF)); STG(pH1 + (KB), dH1 + (SOFF));          \
    }                                                                        \
    FENCE();                                                                 \
    const char* rd = smem + (RD)*SLOT;                                       \
    rdA8(rd + QA,  wm, lr, cbL, af);                                         \
    rdB4(rd + QBF, wn, lr, cbL, bF);                                         \
    rdB4(rd + QBI, wn, lr, cbL, bI);                                         \
    rdB4(rd + QBH, wn, lr, cbL, bH);                                         \
    __builtin_amdgcn_s_setprio(1);                                           \
    mm16(accF, af, bF);                                                      \
    mm16(accI, af, bI);                                                      \
    mm16(accH, af, bH);                                                      \
    __builtin_amdgcn_s_setprio(0);                                           \
  }

__global__ __launch_bounds__(512, 2) void gemm_fused(
    const unsigned short* __restrict__ Abf,   // [M][K] bf16
    const unsigned short* __restrict__ Wc,    // [3][H][K] bf16
    const float* __restrict__ bf_, const float* __restrict__ bi_,
    const float* __restrict__ bh_,
    uint32_t* __restrict__ fv)                // [M][H] packed {f:lo16, v:hi16}
{
  extern __shared__ char smem[];
  int tid = threadIdx.x;
  int bid = blockIdx.x;
  int swz = (bid & 7) * (NWGF/8) + (bid >> 3);  // bijective: NWGF%8==0
  int tn = swz & 7, tm = swz >> 3;
  int m0 = tm*128, n0 = tn*128;
  int lane = tid & 63, wid = tid >> 6;
  int wm = wid >> 2, wn = wid & 3;             // 2 x 4 waves
  int lr = lane & 15, lhi = lane >> 4;
  int cbL = lhi * 16;

  const unsigned short* Ag  = Abf + (size_t)m0 * K_;
  const unsigned short* BFg = Wc + (size_t)n0 * K_;
  const unsigned short* BIg = Wc + (size_t)(H_ + n0) * K_;
  const unsigned short* BHg = Wc + (size_t)(2*H_ + n0) * K_;

  // hoisted per-lane staging addresses
  int o0 = tid*16, o1 = o0 + 8192;
  int r0 = o0 >> 7, c0 = o0 & 127;
  int r1 = o1 >> 7, c1 = o1 & 127;
  size_t lo0 = (size_t)r0*K_ + (size_t)((c0 ^ ((r0 & 7) << 4)) >> 1);
  size_t lo1 = (size_t)r1*K_ + (size_t)((c1 ^ ((r1 & 7) << 4)) >> 1);
  const char* pA0 = (const char*)(Ag  + lo0);
  const char* pA1 = (const char*)(Ag  + lo1);
  const char* pF0 = (const char*)(BFg + lo0);
  const char* pF1 = (const char*)(BFg + lo1);
  const char* pI0 = (const char*)(BIg + lo0);
  const char* pI1 = (const char*)(BIg + lo1);
  const char* pH0 = (const char*)(BHg + lo0);
  const char* pH1 = (const char*)(BHg + lo1);
  char* dA0 = smem + QA  + o0;  char* dA1 = smem + QA  + o1;   // slot0 dests
  char* dF0 = smem + QBF + o0;  char* dF1 = smem + QBF + o1;
  char* dI0 = smem + QBI + o0;  char* dI1 = smem + QBI + o1;
  char* dH0 = smem + QBH + o0;  char* dH1 = smem + QBH + o1;

  f32x4 accF[4][2] = {}, accI[4][2] = {}, accH[4][2] = {};
  bf16v8 af[4][2], bF[2][2], bI[2][2], bH[2][2];

  // prologue: stage tile 0 into slot 0
  STG(pA0, dA0); STG(pA1, dA1);
  STG(pF0, dF0); STG(pF1, dF1);
  STG(pI0, dI0); STG(pI1, dI1);
  STG(pH0, dH0); STG(pH1, dH1);
  pA0 += 128; pA1 += 128; pF0 += 128; pF1 += 128;   // -> tile 1
  pI0 += 128; pI1 += 128; pH0 += 128; pH1 += 128;

  // steps t=0..13 (7 pairs); body(t) stages tile t+1
  for (int tt = 0; tt < 7; ++tt) {
    KSTEP(0, SLOT, 0, 1)       // t even: read slot0, stage -> slot1
    KSTEP(1, 0, 128, 1)        // t odd : read slot1, stage -> slot0
    pA0 += 256; pA1 += 256; pF0 += 256; pF1 += 256;
    pI0 += 256; pI1 += 256; pH0 += 256; pH1 += 256;
  }
  KSTEP(0, SLOT, 0, 1)         // t=14: stage tile 15
  KSTEP(1, 0, 128, 0)          // t=15: no staging

  // epilogue: gate math in-register, write packed bf16x2 {f, v}
  float bfv[2], biv[2], bhv[2];
  #pragma unroll
  for (int j = 0; j < 2; ++j) {
    int col = n0 + wn*32 + j*16 + lr;
    bfv[j] = bf_[col]; biv[j] = bi_[col]; bhv[j] = bh_[col];
  }
  #pragma unroll
  for (int i = 0; i < 4; ++i)
    #pragma unroll
    for (int j = 0; j < 2; ++j) {
      int col = n0 + wn*32 + j*16 + lr;
      int row0 = m0 + wm*64 + i*16 + lhi*4;
      #pragma unroll
      for (int r = 0; r < 4; ++r) {
        float f, v;
        gate_eval(accF[i][j][r] + bfv[j], accI[i][j][r] + biv[j],
                  accH[i][j][r] + bhv[j], f, v);
        fv[(size_t)(row0 + r)*H_ + col] =
            (uint32_t)f2bf(f) | ((uint32_t)f2bf(v) << 16);
      }
    }
}

// ---------------- phase A: per-chunk (A,S) partials from packed fv ----------
__global__ __launch_bounds__(256) void scan_phaseA(
    const uint32_t* __restrict__ fv,
    float* __restrict__ Aw, float* __restrict__ Sw)
{
  int blk = blockIdx.x;                 // 512 = b*64 + c
  int c = blk & 63, b = blk >> 6;
  int h4 = threadIdx.x * 4;
  size_t base = ((size_t)b*T_ + (size_t)c*CHUNK)*H_ + h4;
  float Ap[4] = {1.f,1.f,1.f,1.f}, S[4] = {0.f,0.f,0.f,0.f};
  #pragma unroll 8
  for (int t = 0; t < CHUNK; ++t) {
    uint4 pk = *(const uint4*)(fv + base + (size_t)t*H_);
    uint32_t w[4] = {pk.x, pk.y, pk.z, pk.w};
    #pragma unroll
    for (int u = 0; u < 4; ++u) {
      union { uint32_t u; float f; } cf, cv;
      cf.u = (w[u] & 0xffffu) << 16;
      cv.u = w[u] & 0xffff0000u;
      S[u] = fmaf(cf.f, S[u], cv.f);
      Ap[u] *= cf.f;
    }
  }
  size_t widx = ((size_t)b*NCHUNK + c)*H_ + h4;
  *(float4*)(Aw + widx) = make_float4(Ap[0], Ap[1], Ap[2], Ap[3]);
  *(float4*)(Sw + widx) = make_float4(S[0], S[1], S[2], S[3]);
}

// ---------------- phase B: cross-chunk prefix (tiny) ------------------------
__global__ __launch_bounds__(256) void scan_phaseB(
    const float* __restrict__ Aw, const float* __restrict__ Sw,
    const float* __restrict__ h0, float* __restrict__ Cw)
{
  int i = blockIdx.x*256 + threadIdx.x;    // 0..2047
  int b = i >> 8;
  int h4 = (i & 255) * 4;
  float4 x0 = *(const float4*)(h0 + (size_t)b*H_ + h4);
  float run[4];
  const float* px = (const float*)&x0;
  #pragma unroll
  for (int u = 0; u < 4; ++u)
    run[u] = (px[u] >= 0.f) ? (px[u] + 0.5f) : 1.f/(1.f + __expf(-px[u]));
  #pragma unroll 8
  for (int c = 0; c < NCHUNK; ++c) {
    size_t idx = ((size_t)b*NCHUNK + c)*H_ + h4;
    *(float4*)(Cw + idx) = make_float4(run[0], run[1], run[2], run[3]);
    float4 av = *(const float4*)(Aw + idx);
    float4 sv = *(const float4*)(Sw + idx);
    const float* pa = (const float*)&av;
    const float* ps = (const float*)&sv;
    #pragma unroll
    for (int u = 0; u < 4; ++u) run[u] = fmaf(pa[u], run[u], ps[u]);
  }
}

// ---------------- phase C: replay with carry, write h -----------------------
__global__ __launch_bounds__(256) void scan_phaseC(
    const uint32_t* __restrict__ fv, const float* __restrict__ Cw,
    float* __restrict__ out)
{
  int blk = blockIdx.x;
  int c = blk & 63, b = blk >> 6;
  int h4 = threadIdx.x * 4;
  float4 cw = *(const float4*)(Cw + ((size_t)b*NCHUNK + c)*H_ + h4);
  float hh[4];
  const float* pc = (const float*)&cw;
  #pragma unroll
  for (int u = 0; u < 4; ++u) hh[u] = pc[u];
  size_t base = ((size_t)b*T_ + (size_t)c*CHUNK)*H_ + h4;
  #pragma unroll 8
  for (int t = 0; t < CHUNK; ++t) {
    size_t idx = base + (size_t)t*H_;
    uint4 pk = *(const uint4*)(fv + idx);
    uint32_t w[4] = {pk.x, pk.y, pk.z, pk.w};
    #pragma unroll
    for (int u = 0; u < 4; ++u) {
      union { uint32_t u; float f; } cf, cv;
      cf.u = (w[u] & 0xffffu) << 16;
      cv.u = w[u] & 0xffff0000u;
      hh[u] = fmaf(cf.f, hh[u], cv.f);
    }
    *(float4*)(out + idx) = make_float4(hh[0], hh[1], hh[2], hh[3]);
  }
}

extern "C" void kernel_launch(void* const* d_in, const int* in_sizes, int n_in,
                              void* d_out, int out_size, void* d_ws, size_t ws_size,
                              hipStream_t stream) {
  const float* x   = (const float*)d_in[0];
  const float* h0  = (const float*)d_in[1];
  const float* W_f = (const float*)d_in[2];
  const float* b_f = (const float*)d_in[3];
  const float* W_i = (const float*)d_in[4];
  const float* b_i = (const float*)d_in[5];
  const float* W_h = (const float*)d_in[6];
  const float* b_h = (const float*)d_in[7];
  float* out = (float*)d_out;

  char* ws = (char*)d_ws;
  unsigned short* xb = (unsigned short*)ws;                         // 67.1 MB
  unsigned short* Wc = (unsigned short*)(ws + (size_t)M_*K_*2);     // 6.3 MB
  uint32_t* fv = (uint32_t*)(ws + (size_t)M_*K_*2 + (size_t)3*H_*K_*2); // 134.2 MB
  float* Aw = (float*)(fv + (size_t)M_*H_);                         // 2 MB
  float* Sw = Aw + (size_t)B_*NCHUNK*H_;                            // 2 MB
  float* Cw = Sw + (size_t)B_*NCHUNK*H_;                            // 2 MB

  (void)hipFuncSetAttribute((const void*)gemm_fused,
      hipFuncAttributeMaxDynamicSharedMemorySize, LDS_BYTES);

  cvt_all<<<(M_*K_/8 + 3*H_*K_/8)/256, 256, 0, stream>>>(x, W_f, W_i, W_h, xb, Wc);

  gemm_fused<<<NWGF, 512, LDS_BYTES, stream>>>(xb, Wc, b_f, b_i, b_h, fv);

  scan_phaseA<<<B_*NCHUNK, 256, 0, stream>>>(fv, Aw, Sw);
  scan_phaseB<<<B_*H_/4/256, 256, 0, stream>>>(Aw, Sw, h0, Cw);
  scan_phaseC<<<B_*NCHUNK, 256, 0, stream>>>(fv, Cw, out);
}